// Round 9
// baseline (562.541 us; speedup 1.0000x reference)
//
#include <hip/hip_runtime.h>

// ---------------------------------------------------------------------------
// QAttn (I-BERT int8 fake-quant attention), B=64 N=197 C=768 H=12 D=64
// Round 9: k_gemm_bf16 upgraded (everything else identical to round 8):
//   (1) st-style XOR swizzle, source-side (global src chunk ^ row%8) + same
//       XOR on ds_read chunk -> kills the 16-way 128B-stride bank conflict.
//   (2) double-buffered LDS + counted s_waitcnt vmcnt(8) + raw s_barrier:
//       next K-tile's global_load_lds stays in flight across the MFMA phase
//       (no __syncthreads vmcnt(0) drain).
// GEMM1: A = xhl (hi|lo bf16 split, K=1536, B wraps). GEMM2: A = codes2.
// Attention unchanged from round 5. ws ~179.8 MB (aliased, proven fit).
// ---------------------------------------------------------------------------

#define NB 64
#define NN 197
#define NC 768
#define NH 12
#define ND 64
#define NO3 2304
#define NBH (NB*NH)      // 768
#define NM (NB*NN)       // 12608

typedef unsigned int u32;
typedef unsigned short u16;
typedef unsigned long long u64;
typedef short bf16x8 __attribute__((ext_vector_type(8)));
typedef float f32x4 __attribute__((ext_vector_type(4)));

__device__ __forceinline__ u32 fenc(float f){
  u32 u = __float_as_uint(f);
  return (u & 0x80000000u) ? ~u : (u | 0x80000000u);
}
__device__ __forceinline__ float fdec(u32 e){
  return (e & 0x80000000u) ? __uint_as_float(e ^ 0x80000000u) : __uint_as_float(~e);
}
__device__ __forceinline__ float wmin(float v){
#pragma unroll
  for (int o=32;o>0;o>>=1) v = fminf(v, __shfl_xor(v,o,64));
  return v;
}
__device__ __forceinline__ float wmax(float v){
#pragma unroll
  for (int o=32;o>0;o>>=1) v = fmaxf(v, __shfl_xor(v,o,64));
  return v;
}
__device__ __forceinline__ float fqdq(float x, float s, float z){
  float q = rintf(x/s) + z;
  q = fminf(fmaxf(q, 0.f), 255.f);
  return (q - z) * s;
}
__device__ __forceinline__ u16 tobf(float f){
  u32 u = __float_as_uint(f);
  return (u16)((u + 0x7fffu + ((u >> 16) & 1u)) >> 16);
}
__device__ __forceinline__ float frombf(u16 u){
  return __uint_as_float(((u32)u) << 16);
}
// async global->LDS, 16B per lane (dest must be wave-uniform base + lane*16)
__device__ __forceinline__ void gload16(const void* g, void* l){
  __builtin_amdgcn_global_load_lds(
      (const __attribute__((address_space(1))) void*)g,
      (__attribute__((address_space(3))) void*)l, 16, 0, 0);
}
__device__ __forceinline__ void pipe_fence(){
  __builtin_amdgcn_sched_barrier(0);
}
__device__ __forceinline__ void pipe_barrier(){
  __builtin_amdgcn_sched_barrier(0);
  asm volatile("" ::: "memory");
  __builtin_amdgcn_s_barrier();
  asm volatile("" ::: "memory");
  __builtin_amdgcn_sched_barrier(0);
}

// derive qkv slice quant params from slots[0..5]
__device__ __forceinline__ void qkv_scales(const u32* slots, float* s2, float* z2,
                                           float* s1o, float* z1o){
  float mnr0=fdec(slots[0]), mxr0=fdec(slots[1]);
  float mnr1=fdec(slots[2]), mxr1=fdec(slots[3]);
  float mnr2=fdec(slots[4]), mxr2=fdec(slots[5]);
  float mn1 = fminf(mnr0, fminf(mnr1, mnr2));
  float mx1 = fmaxf(mxr0, fmaxf(mxr1, mxr2));
  float s1 = fmaxf((mx1-mn1)/255.0f, 1e-8f);
  float z1 = rintf(-mn1/s1);
  float a0 = fqdq(mnr0,s1,z1), b0 = fqdq(mxr0,s1,z1);
  float a1 = fqdq(mnr1,s1,z1), b1 = fqdq(mxr1,s1,z1);
  float a2 = fqdq(mnr2,s1,z1), b2 = fqdq(mxr2,s1,z1);
  s2[0] = fmaxf((b0-a0)/255.0f,1e-8f); z2[0] = rintf(-a0/s2[0]);
  s2[1] = fmaxf((b1-a1)/255.0f,1e-8f); z2[1] = rintf(-a1/s2[1]);
  s2[2] = fmaxf((b2-a2)/255.0f,1e-8f); z2[2] = rintf(-a2/s2[2]);
  *s1o = s1; *z1o = z1;
}

// slots[12]: {q_mn,mx, k_mn,mx, v_mn,mx, attn_mn,mx, out_mn,mx, out2_mn,mx}
__global__ void k_init(u32* slots){
  int t = threadIdx.x;
  if (t < 12) slots[t] = (t & 1) ? 0u : 0xFFFFFFFFu;
}

// per-row symmetric int8 weight quant -> bf16 integer codes + f32 row scale
__global__ __launch_bounds__(256) void k_wquant(const float* __restrict__ wqkv,
    const float* __restrict__ wproj, u16* __restrict__ B1, float* __restrict__ s1,
    u16* __restrict__ B2, float* __restrict__ s2){
  int row = blockIdx.x;
  const float* src; u16* dst; float* sd;
  if (row < NO3){ src = wqkv + (size_t)row*NC; dst = B1 + (size_t)row*NC; sd = s1 + row; }
  else { int r2 = row - NO3; src = wproj + (size_t)r2*NC; dst = B2 + (size_t)r2*NC; sd = s2 + r2; }
  int t = threadIdx.x;
  float w0 = src[t], w1 = src[t+256], w2 = src[t+512];
  float am = fmaxf(fabsf(w0), fmaxf(fabsf(w1), fabsf(w2)));
  __shared__ float red[4];
  am = wmax(am);
  if ((t&63)==0) red[t>>6] = am;
  __syncthreads();
  am = fmaxf(fmaxf(red[0],red[1]), fmaxf(red[2],red[3]));
  float s = fmaxf(am / 127.0f, 1e-8f);
  dst[t]     = tobf(fminf(fmaxf(rintf(w0/s), -128.f), 127.f));
  dst[t+256] = tobf(fminf(fmaxf(rintf(w1/s), -128.f), 127.f));
  dst[t+512] = tobf(fminf(fmaxf(rintf(w2/s), -128.f), 127.f));
  if (t==0) *sd = s;
}

// x f32 [M][768] -> xhl bf16 [M][1536] = hi | lo (residual) concat along K
__global__ __launch_bounds__(256) void k_xsplit(const float* __restrict__ x,
    u16* __restrict__ xhl){
  const u32 total = (u32)NM*192u;
  for (u32 i = blockIdx.x*256u + threadIdx.x; i < total; i += gridDim.x*256u){
    u32 row = i / 192u, kc = (i - row*192u)*4u;
    float4 v = *(const float4*)(x + (size_t)row*NC + kc);
    u16 h0=tobf(v.x), h1=tobf(v.y), h2=tobf(v.z), h3=tobf(v.w);
    u64 hp = (u64)h0 | ((u64)h1<<16) | ((u64)h2<<32) | ((u64)h3<<48);
    u64 lp = (u64)tobf(v.x-frombf(h0)) | ((u64)tobf(v.y-frombf(h1))<<16)
           | ((u64)tobf(v.z-frombf(h2))<<32) | ((u64)tobf(v.w-frombf(h3))<<48);
    size_t base = (size_t)row*1536 + kc;
    *(u64*)(xhl + base) = hp;
    *(u64*)(xhl + base + 768) = lp;
  }
}

// attn output f32 [M][768] -> fq integer codes (code - z, exact bf16)
__global__ __launch_bounds__(256) void k_transcode2(const float* __restrict__ p,
    u16* __restrict__ codes2, const u32* __restrict__ slots){
  float mn = fdec(slots[0]), mx = fdec(slots[1]);
  float s = fmaxf((mx-mn)/255.0f, 1e-8f);
  float z = rintf(-mn/s);
  const u32 total = (u32)NM*192u;
  for (u32 i = blockIdx.x*256u + threadIdx.x; i < total; i += gridDim.x*256u){
    u32 row = i / 192u, kc = (i - row*192u)*4u;
    float4 v = *(const float4*)(p + (size_t)row*NC + kc);
    u64 c0 = (u64)tobf(fminf(fmaxf(rintf(v.x/s)+z,0.f),255.f) - z);
    u64 c1 = (u64)tobf(fminf(fmaxf(rintf(v.y/s)+z,0.f),255.f) - z);
    u64 c2 = (u64)tobf(fminf(fmaxf(rintf(v.z/s)+z,0.f),255.f) - z);
    u64 c3 = (u64)tobf(fminf(fmaxf(rintf(v.w/s)+z,0.f),255.f) - z);
    *(u64*)(codes2 + (size_t)row*NC + kc) = c0 | (c1<<16) | (c2<<32) | (c3<<48);
  }
}

// ---------------------------------------------------------------------------
// Pipelined swizzled bf16 GEMM: C[m,o] = (sum_k A[m,k]*B[o,k mod 768])*sc + b
// 128x128 tile, BK=64, 4 waves (2x2, 64x64 each).
// LDS: 2 buffers x (A,B) x [128][64] linear; staged by global_load_lds with
// SOURCE chunk XOR (row%8) pre-swizzle; ds_read applies the same XOR.
// K-loop: STAGE(kt+1) -> vmcnt(8) -> s_barrier -> MFMA(kt) -> s_barrier.
// MODE 0: GEMM1 (KA=1536 hi|lo), slice minmax -> oslot[2*(bx/6)]
// MODE 1: GEMM2 (KA=768 codes), sc *= sA(qslot); global minmax -> oslot[0,1]
// ---------------------------------------------------------------------------
template<int MODE>
__global__ __launch_bounds__(256) void k_gemm_bf16(const u16* __restrict__ A, int KA,
    const u16* __restrict__ Bw, const float* __restrict__ sw,
    const float* __restrict__ bias, float* __restrict__ C, int O,
    const u32* __restrict__ qslot, u32* oslot)
{
  __shared__ u16 Ls[2][2][128*64];   // [buf][A=0/B=1][row*64+col]
  __shared__ float redn[4], redx[4];

  int tid = threadIdx.x;
  int l = tid & 63, w = tid >> 6;
  long m0 = (long)blockIdx.y * 128;
  long o0 = (long)blockIdx.x * 128;

  float sA = 1.f;
  if constexpr (MODE==1){
    float mn = fdec(qslot[0]), mx = fdec(qslot[1]);
    sA = fmaxf((mx-mn)/255.0f, 1e-8f);
  }

  int srow = tid >> 3;                 // 0..31 (staging row base)
  int sch  = tid & 7;                  // dest chunk 0..7 (16B units)
  int sof  = sch * 8;                  // dest col, u16
  int sx   = (sch ^ (srow & 7)) * 8;   // swizzled SOURCE col, u16 (row%8 inv. over q*32)
  long arow[4]; long brow[4];
#pragma unroll
  for (int q=0;q<4;q++){
    long mr = m0 + srow + q*32;
    arow[q] = (mr < NM) ? mr : (long)(NM-1);   // clamp tail (rows never stored)
    brow[q] = o0 + srow + q*32;
  }

  int wm = (w>>1)*64, wn = (w&1)*64;
  int fr = l & 15;
  int c4 = l >> 4;                     // 0..3
  int fx = fr & 7;                     // read-side XOR key

  f32x4 acc[4][4];
#pragma unroll
  for (int mi=0;mi<4;mi++)
#pragma unroll
    for (int ni=0;ni<4;ni++)
#pragma unroll
      for (int j=0;j<4;j++) acc[mi][ni][j] = 0.f;

  int nkt = KA >> 6;
  // prologue: stage tile 0 into buffer 0
#pragma unroll
  for (int q=0;q<4;q++){
    gload16(A  + (size_t)arow[q]*KA + sx, &Ls[0][0][(srow+q*32)*64 + sof]);
    gload16(Bw + (size_t)brow[q]*NC + sx, &Ls[0][1][(srow+q*32)*64 + sof]);
  }

  for (int kt=0; kt<nkt; kt++){
    int cur = kt & 1;
    if (kt+1 < nkt){
      int ka0 = (kt+1)*64;
      int kb0 = (ka0 >= NC) ? (ka0 - NC) : ka0;   // B wraps for KA=1536
      int nb = cur ^ 1;
#pragma unroll
      for (int q=0;q<4;q++){
        gload16(A  + (size_t)arow[q]*KA + ka0 + sx, &Ls[nb][0][(srow+q*32)*64 + sof]);
        gload16(Bw + (size_t)brow[q]*NC + kb0 + sx, &Ls[nb][1][(srow+q*32)*64 + sof]);
      }
      asm volatile("s_waitcnt vmcnt(8)" ::: "memory");   // tile-kt loads done; kt+1 in flight
    } else {
      asm volatile("s_waitcnt vmcnt(0)" ::: "memory");
    }
    pipe_barrier();                      // all waves' tile-kt data visible
    const u16* Ab = &Ls[cur][0][0];
    const u16* Bb = &Ls[cur][1][0];
#pragma unroll
    for (int ks=0; ks<2; ks++){
      int co = (((ks<<2) | c4) ^ fx) * 8;     // swizzled read col (u16)
      bf16x8 bfr[4];
#pragma unroll
      for (int ni=0;ni<4;ni++)
        bfr[ni] = *(const bf16x8*)&Bb[(wn + ni*16 + fr)*64 + co];
#pragma unroll
      for (int mi=0;mi<4;mi++){
        bf16x8 af = *(const bf16x8*)&Ab[(wm + mi*16 + fr)*64 + co];
#pragma unroll
        for (int ni=0;ni<4;ni++)
          acc[mi][ni] = __builtin_amdgcn_mfma_f32_16x16x32_bf16(af, bfr[ni], acc[mi][ni], 0,0,0);
      }
    }
    pipe_barrier();                      // all waves done reading buf[cur]
  }

  float cmn = 3.4e38f, cmx = -3.4e38f;
#pragma unroll
  for (int ni=0;ni<4;ni++){
    long col = o0 + wn + ni*16 + fr;
    float sc = sw[col];
    if constexpr (MODE==1) sc *= sA;
    float bb = bias[col];
#pragma unroll
    for (int mi=0;mi<4;mi++){
      long row0 = m0 + wm + mi*16 + (l>>4)*4;
#pragma unroll
      for (int j=0;j<4;j++){
        long rr = row0 + j;
        if (rr < NM){
          float v = acc[mi][ni][j] * sc + bb;
          C[rr*(long)O + col] = v;
          cmn = fminf(cmn, v); cmx = fmaxf(cmx, v);
        }
      }
    }
  }
  cmn = wmin(cmn); cmx = wmax(cmx);
  if (l==0){ redn[w] = cmn; redx[w] = cmx; }
  __syncthreads();
  if (tid==0){
    float mn = fminf(fminf(redn[0],redn[1]), fminf(redn[2],redn[3]));
    float mx = fmaxf(fmaxf(redx[0],redx[1]), fmaxf(redx[2],redx[3]));
    int sb = (MODE==0) ? 2*(int)(blockIdx.x/6) : 0;
    atomicMin(&oslot[sb],   fenc(mn));
    atomicMax(&oslot[sb+1], fenc(mx));
  }
}

// raw qkv f32 -> per-head bf16 integer codes [sl][bh][n][d]
__global__ __launch_bounds__(256) void k_transcode(const float* __restrict__ qkv,
    u16* __restrict__ codes, const u32* __restrict__ slots){
  float s2[3], z2[3], s1g, z1g;
  qkv_scales(slots, s2, z2, &s1g, &z1g);
  const u32 total = 3u*NBH*NN*16u;
  for (u32 i4 = blockIdx.x*256u + threadIdx.x; i4 < total; i4 += gridDim.x*256u){
    u32 d4 = i4 & 15u;
    u32 t1 = i4 >> 4;
    u32 n  = t1 % NN;
    u32 t2 = t1 / NN;
    u32 bh = t2 % NBH;
    u32 sl = t2 / NBH;
    u32 b = bh / NH, h = bh % NH;
    float4 v = *(const float4*)(qkv + ((size_t)b*NN + n)*NO3 + sl*NC + h*ND + d4*4u);
    float ss = s2[sl], zz = z2[sl];
    u64 c0 = (u64)tobf(fminf(fmaxf(rintf(fqdq(v.x,s1g,z1g)/ss)+zz,0.f),255.f) - zz);
    u64 c1 = (u64)tobf(fminf(fmaxf(rintf(fqdq(v.y,s1g,z1g)/ss)+zz,0.f),255.f) - zz);
    u64 c2 = (u64)tobf(fminf(fmaxf(rintf(fqdq(v.z,s1g,z1g)/ss)+zz,0.f),255.f) - zz);
    u64 c3 = (u64)tobf(fminf(fmaxf(rintf(fqdq(v.w,s1g,z1g)/ss)+zz,0.f),255.f) - zz);
    *(u64*)(codes + ((size_t)sl*NBH*NN + (size_t)bh*NN + n)*ND + d4*4u) =
        c0 | (c1<<16) | (c2<<32) | (c3<<48);
  }
}

// ---------------------------------------------------------------------------
// MFMA attention (unchanged from round 5). grid (4, 768); 4 waves.
// ---------------------------------------------------------------------------
template<int PASS>
__global__ __launch_bounds__(256) void k_attn(const u16* __restrict__ codes,
    float* __restrict__ rowmax, u32* slots, float* __restrict__ outp){
  __shared__ u16 Ks[64*72];
  __shared__ u16 Vt[(PASS==2)?64*72:8];
  __shared__ u16 EsH[(PASS==2)?64*72:8];
  __shared__ u16 EsL[(PASS==2)?64*72:8];
  __shared__ float redn[4], redx[4];

  const u16* qc = codes;
  const u16* kc = codes + (size_t)NBH*NN*ND;
  const u16* vc = codes + 2*(size_t)NBH*NN*ND;

  float s2[3], z2[3], s1g, z1g;
  qkv_scales(slots, s2, z2, &s1g, &z1g);
  float ss = 0.125f * s2[0] * s2[1];
  float sv = s2[2];

  float s=1.f, z=0.f, x0=-1.f, bint=0.f, cint=0.f, as2=0.f, x030=0.f;
  if constexpr (PASS==2){
    float mnA = fdec(slots[6]), mxA = fdec(slots[7]);
    s = fmaxf((mxA-mnA)/255.0f, 1e-8f);
    z = rintf(-mnA/s);
    x0 = floorf(-0.6931471805599453f / s);
    bint = floorf((float)(0.96963238/0.35815147) / s);
    cint = floorf((float)(1.0/0.35815147) / (s*s));
    as2 = (0.35815147f*s)*s;
    x030 = 30.f*x0;
  }

  int tid = threadIdx.x;
  int l = tid & 63, w = tid >> 6;
  int bh = blockIdx.y, nt = blockIdx.x;
  int lr = l & 15, lk = l >> 4;

  int qrow = nt*64 + w*16 + lr;
  bf16x8 aq0 = {}, aq1 = {};
  if (qrow < NN){
    const u16* qp = qc + ((size_t)bh*NN + qrow)*ND + lk*8;
    aq0 = *(const bf16x8*)qp;
    aq1 = *(const bf16x8*)(qp + 32);
  }

  int qr[4];
#pragma unroll
  for (int j=0;j<4;j++) qr[j] = nt*64 + w*16 + lk*4 + j;

  float rcode[4] = {0.f,0.f,0.f,0.f};
  if constexpr (PASS==2){
#pragma unroll
    for (int j=0;j<4;j++)
      if (qr[j] < NN)
        rcode[j] = fminf(fmaxf(rintf(rowmax[(size_t)bh*NN + qr[j]]/s)+z,0.f),255.f);
  }

  float gmn = 3.4e38f, gmx = -3.4e38f;
  float rmx[4] = {-3.4e38f,-3.4e38f,-3.4e38f,-3.4e38f};
  float den[4] = {0.f,0.f,0.f,0.f};
  f32x4 num[4];
#pragma unroll
  for (int dt=0;dt<4;dt++)
#pragma unroll
    for (int j=0;j<4;j++) num[dt][j] = 0.f;

  for (int mt=0; mt<4; mt++){
    __syncthreads();
#pragma unroll
    for (int rep=0; rep<2; rep++){
      int task = tid + rep*256;
      int row = task >> 3, dc = task & 7;
      int grow = mt*64 + row;
      bf16x8 kv8 = {};
      if (grow < NN) kv8 = *(const bf16x8*)(kc + ((size_t)bh*NN + grow)*ND + dc*8);
      *(bf16x8*)&Ks[row*72 + dc*8] = kv8;
      if constexpr (PASS==2){
        bf16x8 vv8 = {};
        if (grow < NN) vv8 = *(const bf16x8*)(vc + ((size_t)bh*NN + grow)*ND + dc*8);
#pragma unroll
        for (int jj=0;jj<8;jj++) Vt[(dc*8+jj)*72 + row] = (u16)vv8[jj];
      }
    }
    __syncthreads();

    f32x4 sca[4];
#pragma unroll
    for (int ct=0;ct<4;ct++)
#pragma unroll
      for (int j=0;j<4;j++) sca[ct][j] = 0.f;
#pragma unroll
    for (int ct=0;ct<4;ct++){
      bf16x8 bk0 = *(const bf16x8*)&Ks[(ct*16 + lr)*72 + lk*8];
      bf16x8 bk1 = *(const bf16x8*)&Ks[(ct*16 + lr)*72 + 32 + lk*8];
      sca[ct] = __builtin_amdgcn_mfma_f32_16x16x32_bf16(aq0, bk0, sca[ct], 0,0,0);
      sca[ct] = __builtin_amdgcn_mfma_f32_16x16x32_bf16(aq1, bk1, sca[ct], 0,0,0);
    }

    if constexpr (PASS==1){
#pragma unroll
      for (int ct=0;ct<4;ct++){
        int m = mt*64 + ct*16 + lr;
        bool mv = m < NN;
#pragma unroll
        for (int j=0;j<4;j++){
          float sc = sca[ct][j] * ss;
          if (mv && qr[j] < NN){
            gmn = fminf(gmn, sc); gmx = fmaxf(gmx, sc);
            rmx[j] = fmaxf(rmx[j], sc);
          }
        }
      }
    } else {
#pragma unroll
      for (int ct=0;ct<4;ct++){
        int m = mt*64 + ct*16 + lr;
        bool mv = m < NN;
#pragma unroll
        for (int j=0;j<4;j++){
          float e = 0.f;
          if (mv && qr[j] < NN){
            float sc = sca[ct][j] * ss;
            float code = fminf(fmaxf(rintf(sc/s)+z, 0.f), 255.f);
            float xx = fmaxf(code - rcode[j], x030);
            float qe = floorf(xx / x0);
            float rr = xx - x0*qe;
            float p = rr*(rr + bint) + cint;
            e = scalbnf(p, -(int)qe) * as2;
            den[j] += e;
          }
          u16 eh = tobf(e);
          int ea = (w*16 + lk*4 + j)*72 + ct*16 + lr;
          EsH[ea] = eh;
          EsL[ea] = tobf(e - frombf(eh));
        }
      }
      __syncthreads();
#pragma unroll
      for (int ks=0; ks<2; ks++){
        bf16x8 ahh = *(const bf16x8*)&EsH[(w*16 + lr)*72 + ks*32 + lk*8];
        bf16x8 ahl = *(const bf16x8*)&EsL[(w*16 + lr)*72 + ks*32 + lk*8];
#pragma unroll
        for (int dt=0; dt<4; dt++){
          bf16x8 bv = *(const bf16x8*)&Vt[(dt*16 + lr)*72 + ks*32 + lk*8];
          num[dt] = __builtin_amdgcn_mfma_f32_16x16x32_bf16(ahh, bv, num[dt], 0,0,0);
          num[dt] = __builtin_amdgcn_mfma_f32_16x16x32_bf16(ahl, bv, num[dt], 0,0,0);
        }
      }
    }
  }

  if constexpr (PASS==1){
#pragma unroll
    for (int j=0;j<4;j++){
#pragma unroll
      for (int o=1;o<16;o<<=1) rmx[j] = fmaxf(rmx[j], __shfl_xor(rmx[j], o, 64));
    }
    if (lr == 0){
#pragma unroll
      for (int j=0;j<4;j++)
        if (qr[j] < NN) rowmax[(size_t)bh*NN + qr[j]] = rmx[j];
    }
    gmn = wmin(gmn); gmx = wmax(gmx);
    if (l==0){ redn[w]=gmn; redx[w]=gmx; }
    __syncthreads();
    if (tid==0){
      float mn = fminf(fminf(redn[0],redn[1]), fminf(redn[2],redn[3]));
      float mx = fmaxf(fmaxf(redx[0],redx[1]), fmaxf(redx[2],redx[3]));
      atomicMin(&slots[6], fenc(mn));
      atomicMax(&slots[7], fenc(mx));
    }
  } else {
#pragma unroll
    for (int j=0;j<4;j++){
#pragma unroll
      for (int o=1;o<16;o<<=1) den[j] += __shfl_xor(den[j], o, 64);
    }
    int b = bh/NH, h = bh - b*NH;
    float gmn2 = 3.4e38f, gmx2 = -3.4e38f;
#pragma unroll
    for (int dt=0;dt<4;dt++){
#pragma unroll
      for (int j=0;j<4;j++){
        if (qr[j] < NN){
          float oo = num[dt][j] * sv / den[j];
          outp[((size_t)b*NN + qr[j])*NC + h*ND + dt*16 + lr] = oo;
          gmn2 = fminf(gmn2, oo); gmx2 = fmaxf(gmx2, oo);
        }
      }
    }
    gmn2 = wmin(gmn2); gmx2 = wmax(gmx2);
    if (l==0){ redn[w]=gmn2; redx[w]=gmx2; }
    __syncthreads();
    if (tid==0){
      float mn = fminf(fminf(redn[0],redn[1]), fminf(redn[2],redn[3]));
      float mx = fmaxf(fmaxf(redx[0],redx[1]), fmaxf(redx[2],redx[3]));
      atomicMin(&slots[8], fenc(mn));
      atomicMax(&slots[9], fenc(mx));
    }
  }
}

__global__ __launch_bounds__(256) void k_fq_inplace(float* x, long n4, const u32* __restrict__ slots){
  float mn = fdec(slots[0]), mx = fdec(slots[1]);
  float s = fmaxf((mx-mn)/255.0f, 1e-8f);
  float z = rintf(-mn/s);
  for (long i = (long)blockIdx.x*blockDim.x + threadIdx.x; i < n4; i += (long)gridDim.x*blockDim.x){
    float4 v = ((float4*)x)[i];
    v.x = fqdq(v.x,s,z); v.y = fqdq(v.y,s,z); v.z = fqdq(v.z,s,z); v.w = fqdq(v.w,s,z);
    ((float4*)x)[i] = v;
  }
}

extern "C" void kernel_launch(void* const* d_in, const int* in_sizes, int n_in,
                              void* d_out, int out_size, void* d_ws, size_t ws_size,
                              hipStream_t stream) {
  (void)in_sizes; (void)n_in; (void)out_size; (void)ws_size;
  const float* x      = (const float*)d_in[0];
  const float* w_qkv  = (const float*)d_in[1];
  const float* b_qkv  = (const float*)d_in[2];
  const float* w_proj = (const float*)d_in[3];
  const float* b_proj = (const float*)d_in[4];
  float* out = (float*)d_out;

  u32*   slots  = (u32*)d_ws;
  u16*   B1     = (u16*)((char*)d_ws + 256);        // 2304*768 u16
  u16*   B2     = B1 + (size_t)NO3*NC;              //  768*768 u16
  float* s1     = (float*)(B2 + (size_t)NC*NC);     // 2304
  float* s2     = s1 + NO3;                         //  768
  float* rowmax = s2 + NC;                          // 768*197
  float* qkv    = rowmax + (size_t)NBH*NN;          // 12608*2304 f32 (116.2 MB)
  u16*   codesR = (u16*)(qkv + (size_t)NM*NO3);     // 58.1 MB shared region:
  u16*   xhl    = codesR;                           //   [M][1536] bf16, dies at transcode
  u16*   codes  = codesR;                           //   attn codes, dies at transcode2
  u16*   codes2 = codesR;                           //   [M][768] bf16
  float* outpv  = qkv;                              // ALIAS: qkv raw dead after transcode

  k_init<<<1, 64, 0, stream>>>(slots);
  k_wquant<<<NO3 + NC, 256, 0, stream>>>(w_qkv, w_proj, B1, s1, B2, s2);
  k_xsplit<<<1024, 256, 0, stream>>>(x, xhl);
  k_gemm_bf16<0><<<dim3(NO3/128, 99), 256, 0, stream>>>(xhl, 1536, B1, s1, b_qkv, qkv, NO3, nullptr, slots);
  k_transcode<<<2048, 256, 0, stream>>>(qkv, codes, slots);
  k_attn<1><<<dim3(4, NBH), 256, 0, stream>>>(codes, rowmax, slots, nullptr);
  k_attn<2><<<dim3(4, NBH), 256, 0, stream>>>(codes, rowmax, slots, outpv);
  k_transcode2<<<1024, 256, 0, stream>>>(outpv, codes2, slots + 8);
  k_gemm_bf16<1><<<dim3(NC/128, 99), 256, 0, stream>>>(codes2, 768, B2, s2, b_proj, out, NC, slots + 8, slots + 10);
  k_fq_inplace<<<1024, 256, 0, stream>>>(out, (long)NM*NC/4, slots + 10);
}

// Round 11
// 555.078 us; speedup vs baseline: 1.0134x; 1.0134x over previous
//
#include <hip/hip_runtime.h>

// ---------------------------------------------------------------------------
// QAttn (I-BERT int8 fake-quant attention), B=64 N=197 C=768 H=12 D=64
// Round 10 (resubmit; broker timeout): + T1 XCD-chunked bijective block
// swizzle on both GEMMs (m204): 1D grid; each XCD gets ~nwg/8 CONSECUTIVE
// row-major tiles -> A-panels fetched into one XCD L2 instead of eight.
// (FETCH was 5x ideal.) GEMM internals unchanged from round 9 (0-conflict
// XOR swizzle + dbuf + counted vmcnt). Attention unchanged from round 5.
// ws ~179.8 MB.
// ---------------------------------------------------------------------------

#define NB 64
#define NN 197
#define NC 768
#define NH 12
#define ND 64
#define NO3 2304
#define NBH (NB*NH)      // 768
#define NM (NB*NN)       // 12608

typedef unsigned int u32;
typedef unsigned short u16;
typedef unsigned long long u64;
typedef short bf16x8 __attribute__((ext_vector_type(8)));
typedef float f32x4 __attribute__((ext_vector_type(4)));

__device__ __forceinline__ u32 fenc(float f){
  u32 u = __float_as_uint(f);
  return (u & 0x80000000u) ? ~u : (u | 0x80000000u);
}
__device__ __forceinline__ float fdec(u32 e){
  return (e & 0x80000000u) ? __uint_as_float(e ^ 0x80000000u) : __uint_as_float(~e);
}
__device__ __forceinline__ float wmin(float v){
#pragma unroll
  for (int o=32;o>0;o>>=1) v = fminf(v, __shfl_xor(v,o,64));
  return v;
}
__device__ __forceinline__ float wmax(float v){
#pragma unroll
  for (int o=32;o>0;o>>=1) v = fmaxf(v, __shfl_xor(v,o,64));
  return v;
}
__device__ __forceinline__ float fqdq(float x, float s, float z){
  float q = rintf(x/s) + z;
  q = fminf(fmaxf(q, 0.f), 255.f);
  return (q - z) * s;
}
__device__ __forceinline__ u16 tobf(float f){
  u32 u = __float_as_uint(f);
  return (u16)((u + 0x7fffu + ((u >> 16) & 1u)) >> 16);
}
__device__ __forceinline__ float frombf(u16 u){
  return __uint_as_float(((u32)u) << 16);
}
// async global->LDS, 16B per lane (dest must be wave-uniform base + lane*16)
__device__ __forceinline__ void gload16(const void* g, void* l){
  __builtin_amdgcn_global_load_lds(
      (const __attribute__((address_space(1))) void*)g,
      (__attribute__((address_space(3))) void*)l, 16, 0, 0);
}
__device__ __forceinline__ void pipe_barrier(){
  __builtin_amdgcn_sched_barrier(0);
  asm volatile("" ::: "memory");
  __builtin_amdgcn_s_barrier();
  asm volatile("" ::: "memory");
  __builtin_amdgcn_sched_barrier(0);
}

// derive qkv slice quant params from slots[0..5]
__device__ __forceinline__ void qkv_scales(const u32* slots, float* s2, float* z2,
                                           float* s1o, float* z1o){
  float mnr0=fdec(slots[0]), mxr0=fdec(slots[1]);
  float mnr1=fdec(slots[2]), mxr1=fdec(slots[3]);
  float mnr2=fdec(slots[4]), mxr2=fdec(slots[5]);
  float mn1 = fminf(mnr0, fminf(mnr1, mnr2));
  float mx1 = fmaxf(mxr0, fmaxf(mxr1, mxr2));
  float s1 = fmaxf((mx1-mn1)/255.0f, 1e-8f);
  float z1 = rintf(-mn1/s1);
  float a0 = fqdq(mnr0,s1,z1), b0 = fqdq(mxr0,s1,z1);
  float a1 = fqdq(mnr1,s1,z1), b1 = fqdq(mxr1,s1,z1);
  float a2 = fqdq(mnr2,s1,z1), b2 = fqdq(mxr2,s1,z1);
  s2[0] = fmaxf((b0-a0)/255.0f,1e-8f); z2[0] = rintf(-a0/s2[0]);
  s2[1] = fmaxf((b1-a1)/255.0f,1e-8f); z2[1] = rintf(-a1/s2[1]);
  s2[2] = fmaxf((b2-a2)/255.0f,1e-8f); z2[2] = rintf(-a2/s2[2]);
  *s1o = s1; *z1o = z1;
}

// slots[12]: {q_mn,mx, k_mn,mx, v_mn,mx, attn_mn,mx, out_mn,mx, out2_mn,mx}
__global__ void k_init(u32* slots){
  int t = threadIdx.x;
  if (t < 12) slots[t] = (t & 1) ? 0u : 0xFFFFFFFFu;
}

// per-row symmetric int8 weight quant -> bf16 integer codes + f32 row scale
__global__ __launch_bounds__(256) void k_wquant(const float* __restrict__ wqkv,
    const float* __restrict__ wproj, u16* __restrict__ B1, float* __restrict__ s1,
    u16* __restrict__ B2, float* __restrict__ s2){
  int row = blockIdx.x;
  const float* src; u16* dst; float* sd;
  if (row < NO3){ src = wqkv + (size_t)row*NC; dst = B1 + (size_t)row*NC; sd = s1 + row; }
  else { int r2 = row - NO3; src = wproj + (size_t)r2*NC; dst = B2 + (size_t)r2*NC; sd = s2 + r2; }
  int t = threadIdx.x;
  float w0 = src[t], w1 = src[t+256], w2 = src[t+512];
  float am = fmaxf(fabsf(w0), fmaxf(fabsf(w1), fabsf(w2)));
  __shared__ float red[4];
  am = wmax(am);
  if ((t&63)==0) red[t>>6] = am;
  __syncthreads();
  am = fmaxf(fmaxf(red[0],red[1]), fmaxf(red[2],red[3]));
  float s = fmaxf(am / 127.0f, 1e-8f);
  dst[t]     = tobf(fminf(fmaxf(rintf(w0/s), -128.f), 127.f));
  dst[t+256] = tobf(fminf(fmaxf(rintf(w1/s), -128.f), 127.f));
  dst[t+512] = tobf(fminf(fmaxf(rintf(w2/s), -128.f), 127.f));
  if (t==0) *sd = s;
}

// x f32 [M][768] -> xhl bf16 [M][1536] = hi | lo (residual) concat along K
__global__ __launch_bounds__(256) void k_xsplit(const float* __restrict__ x,
    u16* __restrict__ xhl){
  const u32 total = (u32)NM*192u;
  for (u32 i = blockIdx.x*256u + threadIdx.x; i < total; i += gridDim.x*256u){
    u32 row = i / 192u, kc = (i - row*192u)*4u;
    float4 v = *(const float4*)(x + (size_t)row*NC + kc);
    u16 h0=tobf(v.x), h1=tobf(v.y), h2=tobf(v.z), h3=tobf(v.w);
    u64 hp = (u64)h0 | ((u64)h1<<16) | ((u64)h2<<32) | ((u64)h3<<48);
    u64 lp = (u64)tobf(v.x-frombf(h0)) | ((u64)tobf(v.y-frombf(h1))<<16)
           | ((u64)tobf(v.z-frombf(h2))<<32) | ((u64)tobf(v.w-frombf(h3))<<48);
    size_t base = (size_t)row*1536 + kc;
    *(u64*)(xhl + base) = hp;
    *(u64*)(xhl + base + 768) = lp;
  }
}

// attn output f32 [M][768] -> fq integer codes (code - z, exact bf16)
__global__ __launch_bounds__(256) void k_transcode2(const float* __restrict__ p,
    u16* __restrict__ codes2, const u32* __restrict__ slots){
  float mn = fdec(slots[0]), mx = fdec(slots[1]);
  float s = fmaxf((mx-mn)/255.0f, 1e-8f);
  float z = rintf(-mn/s);
  const u32 total = (u32)NM*192u;
  for (u32 i = blockIdx.x*256u + threadIdx.x; i < total; i += gridDim.x*256u){
    u32 row = i / 192u, kc = (i - row*192u)*4u;
    float4 v = *(const float4*)(p + (size_t)row*NC + kc);
    u64 c0 = (u64)tobf(fminf(fmaxf(rintf(v.x/s)+z,0.f),255.f) - z);
    u64 c1 = (u64)tobf(fminf(fmaxf(rintf(v.y/s)+z,0.f),255.f) - z);
    u64 c2 = (u64)tobf(fminf(fmaxf(rintf(v.z/s)+z,0.f),255.f) - z);
    u64 c3 = (u64)tobf(fminf(fmaxf(rintf(v.w/s)+z,0.f),255.f) - z);
    *(u64*)(codes2 + (size_t)row*NC + kc) = c0 | (c1<<16) | (c2<<32) | (c3<<48);
  }
}

// ---------------------------------------------------------------------------
// Pipelined swizzled bf16 GEMM, 1D grid + XCD-chunked bijective swizzle (T1).
// C[m,o] = (sum_k A[m,k]*B[o,k mod 768])*sc + bias; 128x128 tile, BK=64,
// 4 waves. LDS dbuf, source-XOR bank swizzle, counted vmcnt(8), raw barriers.
// ncol = number of 128-wide column tiles (18 for GEMM1, 6 for GEMM2).
// MODE 0: GEMM1 (KA=1536 hi|lo), slice minmax -> oslot[2*(bcol/6)]
// MODE 1: GEMM2 (KA=768 codes), sc *= sA(qslot); global minmax -> oslot[0,1]
// ---------------------------------------------------------------------------
template<int MODE>
__global__ __launch_bounds__(256) void k_gemm_bf16(const u16* __restrict__ A, int KA,
    const u16* __restrict__ Bw, const float* __restrict__ sw,
    const float* __restrict__ bias, float* __restrict__ C, int O, int ncol,
    const u32* __restrict__ qslot, u32* oslot)
{
  __shared__ u16 Ls[2][2][128*64];   // [buf][A=0/B=1][row*64+col]
  __shared__ float redn[4], redx[4];

  int tid = threadIdx.x;
  int l = tid & 63, w = tid >> 6;

  // T1: bijective chunked XCD swizzle (m204). HW round-robins blockIdx.x
  // across 8 XCDs; this remap gives each XCD ~nwg/8 CONSECUTIVE row-major
  // tiles -> A-panel reuse stays within one XCD's L2.
  int nwg = (int)gridDim.x;
  int bid = (int)blockIdx.x;
  int cq = nwg >> 3, cr = nwg & 7;
  int xcd = bid & 7, ci = bid >> 3;
  int wgid = (xcd < cr ? xcd*(cq+1) : cr*(cq+1) + (xcd-cr)*cq) + ci;
  int brow = wgid / ncol, bcol = wgid - brow*ncol;
  long m0 = (long)brow * 128;
  long o0 = (long)bcol * 128;

  float sA = 1.f;
  if constexpr (MODE==1){
    float mn = fdec(qslot[0]), mx = fdec(qslot[1]);
    sA = fmaxf((mx-mn)/255.0f, 1e-8f);
  }

  int srow = tid >> 3;                 // 0..31 (staging row base)
  int sch  = tid & 7;                  // dest chunk 0..7 (16B units)
  int sof  = sch * 8;                  // dest col, u16
  int sx   = (sch ^ (srow & 7)) * 8;   // swizzled SOURCE col, u16
  long arow[4]; long brow4[4];
#pragma unroll
  for (int q=0;q<4;q++){
    long mr = m0 + srow + q*32;
    arow[q] = (mr < NM) ? mr : (long)(NM-1);   // clamp tail (rows never stored)
    brow4[q] = o0 + srow + q*32;
  }

  int wm = (w>>1)*64, wn = (w&1)*64;
  int fr = l & 15;
  int c4 = l >> 4;                     // 0..3
  int fx = fr & 7;                     // read-side XOR key

  f32x4 acc[4][4];
#pragma unroll
  for (int mi=0;mi<4;mi++)
#pragma unroll
    for (int ni=0;ni<4;ni++)
#pragma unroll
      for (int j=0;j<4;j++) acc[mi][ni][j] = 0.f;

  int nkt = KA >> 6;
  // prologue: stage tile 0 into buffer 0
#pragma unroll
  for (int q=0;q<4;q++){
    gload16(A  + (size_t)arow[q]*KA + sx, &Ls[0][0][(srow+q*32)*64 + sof]);
    gload16(Bw + (size_t)brow4[q]*NC + sx, &Ls[0][1][(srow+q*32)*64 + sof]);
  }

  for (int kt=0; kt<nkt; kt++){
    int cur = kt & 1;
    if (kt+1 < nkt){
      int ka0 = (kt+1)*64;
      int kb0 = (ka0 >= NC) ? (ka0 - NC) : ka0;   // B wraps for KA=1536
      int nb = cur ^ 1;
#pragma unroll
      for (int q=0;q<4;q++){
        gload16(A  + (size_t)arow[q]*KA + ka0 + sx, &Ls[nb][0][(srow+q*32)*64 + sof]);
        gload16(Bw + (size_t)brow4[q]*NC + kb0 + sx, &Ls[nb][1][(srow+q*32)*64 + sof]);
      }
      asm volatile("s_waitcnt vmcnt(8)" ::: "memory");   // tile-kt done; kt+1 in flight
    } else {
      asm volatile("s_waitcnt vmcnt(0)" ::: "memory");
    }
    pipe_barrier();                      // all waves' tile-kt data visible
    const u16* Ab = &Ls[cur][0][0];
    const u16* Bb = &Ls[cur][1][0];
#pragma unroll
    for (int ks=0; ks<2; ks++){
      int co = (((ks<<2) | c4) ^ fx) * 8;     // swizzled read col (u16)
      bf16x8 bfr[4];
#pragma unroll
      for (int ni=0;ni<4;ni++)
        bfr[ni] = *(const bf16x8*)&Bb[(wn + ni*16 + fr)*64 + co];
#pragma unroll
      for (int mi=0;mi<4;mi++){
        bf16x8 af = *(const bf16x8*)&Ab[(wm + mi*16 + fr)*64 + co];
#pragma unroll
        for (int ni=0;ni<4;ni++)
          acc[mi][ni] = __builtin_amdgcn_mfma_f32_16x16x32_bf16(af, bfr[ni], acc[mi][ni], 0,0,0);
      }
    }
    pipe_barrier();                      // all waves done reading buf[cur]
  }

  float cmn = 3.4e38f, cmx = -3.4e38f;
#pragma unroll
  for (int ni=0;ni<4;ni++){
    long col = o0 + wn + ni*16 + fr;
    float sc = sw[col];
    if constexpr (MODE==1) sc *= sA;
    float bb = bias[col];
#pragma unroll
    for (int mi=0;mi<4;mi++){
      long row0 = m0 + wm + mi*16 + (l>>4)*4;
#pragma unroll
      for (int j=0;j<4;j++){
        long rr = row0 + j;
        if (rr < NM){
          float v = acc[mi][ni][j] * sc + bb;
          C[rr*(long)O + col] = v;
          cmn = fminf(cmn, v); cmx = fmaxf(cmx, v);
        }
      }
    }
  }
  cmn = wmin(cmn); cmx = wmax(cmx);
  if (l==0){ redn[w] = cmn; redx[w] = cmx; }
  __syncthreads();
  if (tid==0){
    float mn = fminf(fminf(redn[0],redn[1]), fminf(redn[2],redn[3]));
    float mx = fmaxf(fmaxf(redx[0],redx[1]), fmaxf(redx[2],redx[3]));
    int sb = (MODE==0) ? 2*(bcol/6) : 0;
    atomicMin(&oslot[sb],   fenc(mn));
    atomicMax(&oslot[sb+1], fenc(mx));
  }
}

// raw qkv f32 -> per-head bf16 integer codes [sl][bh][n][d]
__global__ __launch_bounds__(256) void k_transcode(const float* __restrict__ qkv,
    u16* __restrict__ codes, const u32* __restrict__ slots){
  float s2[3], z2[3], s1g, z1g;
  qkv_scales(slots, s2, z2, &s1g, &z1g);
  const u32 total = 3u*NBH*NN*16u;
  for (u32 i4 = blockIdx.x*256u + threadIdx.x; i4 < total; i4 += gridDim.x*256u){
    u32 d4 = i4 & 15u;
    u32 t1 = i4 >> 4;
    u32 n  = t1 % NN;
    u32 t2 = t1 / NN;
    u32 bh = t2 % NBH;
    u32 sl = t2 / NBH;
    u32 b = bh / NH, h = bh % NH;
    float4 v = *(const float4*)(qkv + ((size_t)b*NN + n)*NO3 + sl*NC + h*ND + d4*4u);
    float ss = s2[sl], zz = z2[sl];
    u64 c0 = (u64)tobf(fminf(fmaxf(rintf(fqdq(v.x,s1g,z1g)/ss)+zz,0.f),255.f) - zz);
    u64 c1 = (u64)tobf(fminf(fmaxf(rintf(fqdq(v.y,s1g,z1g)/ss)+zz,0.f),255.f) - zz);
    u64 c2 = (u64)tobf(fminf(fmaxf(rintf(fqdq(v.z,s1g,z1g)/ss)+zz,0.f),255.f) - zz);
    u64 c3 = (u64)tobf(fminf(fmaxf(rintf(fqdq(v.w,s1g,z1g)/ss)+zz,0.f),255.f) - zz);
    *(u64*)(codes + ((size_t)sl*NBH*NN + (size_t)bh*NN + n)*ND + d4*4u) =
        c0 | (c1<<16) | (c2<<32) | (c3<<48);
  }
}

// ---------------------------------------------------------------------------
// MFMA attention (unchanged from round 5). grid (4, 768); 4 waves.
// ---------------------------------------------------------------------------
template<int PASS>
__global__ __launch_bounds__(256) void k_attn(const u16* __restrict__ codes,
    float* __restrict__ rowmax, u32* slots, float* __restrict__ outp){
  __shared__ u16 Ks[64*72];
  __shared__ u16 Vt[(PASS==2)?64*72:8];
  __shared__ u16 EsH[(PASS==2)?64*72:8];
  __shared__ u16 EsL[(PASS==2)?64*72:8];
  __shared__ float redn[4], redx[4];

  const u16* qc = codes;
  const u16* kc = codes + (size_t)NBH*NN*ND;
  const u16* vc = codes + 2*(size_t)NBH*NN*ND;

  float s2[3], z2[3], s1g, z1g;
  qkv_scales(slots, s2, z2, &s1g, &z1g);
  float ss = 0.125f * s2[0] * s2[1];
  float sv = s2[2];

  float s=1.f, z=0.f, x0=-1.f, bint=0.f, cint=0.f, as2=0.f, x030=0.f;
  if constexpr (PASS==2){
    float mnA = fdec(slots[6]), mxA = fdec(slots[7]);
    s = fmaxf((mxA-mnA)/255.0f, 1e-8f);
    z = rintf(-mnA/s);
    x0 = floorf(-0.6931471805599453f / s);
    bint = floorf((float)(0.96963238/0.35815147) / s);
    cint = floorf((float)(1.0/0.35815147) / (s*s));
    as2 = (0.35815147f*s)*s;
    x030 = 30.f*x0;
  }

  int tid = threadIdx.x;
  int l = tid & 63, w = tid >> 6;
  int bh = blockIdx.y, nt = blockIdx.x;
  int lr = l & 15, lk = l >> 4;

  int qrow = nt*64 + w*16 + lr;
  bf16x8 aq0 = {}, aq1 = {};
  if (qrow < NN){
    const u16* qp = qc + ((size_t)bh*NN + qrow)*ND + lk*8;
    aq0 = *(const bf16x8*)qp;
    aq1 = *(const bf16x8*)(qp + 32);
  }

  int qr[4];
#pragma unroll
  for (int j=0;j<4;j++) qr[j] = nt*64 + w*16 + lk*4 + j;

  float rcode[4] = {0.f,0.f,0.f,0.f};
  if constexpr (PASS==2){
#pragma unroll
    for (int j=0;j<4;j++)
      if (qr[j] < NN)
        rcode[j] = fminf(fmaxf(rintf(rowmax[(size_t)bh*NN + qr[j]]/s)+z,0.f),255.f);
  }

  float gmn = 3.4e38f, gmx = -3.4e38f;
  float rmx[4] = {-3.4e38f,-3.4e38f,-3.4e38f,-3.4e38f};
  float den[4] = {0.f,0.f,0.f,0.f};
  f32x4 num[4];
#pragma unroll
  for (int dt=0;dt<4;dt++)
#pragma unroll
    for (int j=0;j<4;j++) num[dt][j] = 0.f;

  for (int mt=0; mt<4; mt++){
    __syncthreads();
#pragma unroll
    for (int rep=0; rep<2; rep++){
      int task = tid + rep*256;
      int row = task >> 3, dc = task & 7;
      int grow = mt*64 + row;
      bf16x8 kv8 = {};
      if (grow < NN) kv8 = *(const bf16x8*)(kc + ((size_t)bh*NN + grow)*ND + dc*8);
      *(bf16x8*)&Ks[row*72 + dc*8] = kv8;
      if constexpr (PASS==2){
        bf16x8 vv8 = {};
        if (grow < NN) vv8 = *(const bf16x8*)(vc + ((size_t)bh*NN + grow)*ND + dc*8);
#pragma unroll
        for (int jj=0;jj<8;jj++) Vt[(dc*8+jj)*72 + row] = (u16)vv8[jj];
      }
    }
    __syncthreads();

    f32x4 sca[4];
#pragma unroll
    for (int ct=0;ct<4;ct++)
#pragma unroll
      for (int j=0;j<4;j++) sca[ct][j] = 0.f;
#pragma unroll
    for (int ct=0;ct<4;ct++){
      bf16x8 bk0 = *(const bf16x8*)&Ks[(ct*16 + lr)*72 + lk*8];
      bf16x8 bk1 = *(const bf16x8*)&Ks[(ct*16 + lr)*72 + 32 + lk*8];
      sca[ct] = __builtin_amdgcn_mfma_f32_16x16x32_bf16(aq0, bk0, sca[ct], 0,0,0);
      sca[ct] = __builtin_amdgcn_mfma_f32_16x16x32_bf16(aq1, bk1, sca[ct], 0,0,0);
    }

    if constexpr (PASS==1){
#pragma unroll
      for (int ct=0;ct<4;ct++){
        int m = mt*64 + ct*16 + lr;
        bool mv = m < NN;
#pragma unroll
        for (int j=0;j<4;j++){
          float sc = sca[ct][j] * ss;
          if (mv && qr[j] < NN){
            gmn = fminf(gmn, sc); gmx = fmaxf(gmx, sc);
            rmx[j] = fmaxf(rmx[j], sc);
          }
        }
      }
    } else {
#pragma unroll
      for (int ct=0;ct<4;ct++){
        int m = mt*64 + ct*16 + lr;
        bool mv = m < NN;
#pragma unroll
        for (int j=0;j<4;j++){
          float e = 0.f;
          if (mv && qr[j] < NN){
            float sc = sca[ct][j] * ss;
            float code = fminf(fmaxf(rintf(sc/s)+z, 0.f), 255.f);
            float xx = fmaxf(code - rcode[j], x030);
            float qe = floorf(xx / x0);
            float rr = xx - x0*qe;
            float p = rr*(rr + bint) + cint;
            e = scalbnf(p, -(int)qe) * as2;
            den[j] += e;
          }
          u16 eh = tobf(e);
          int ea = (w*16 + lk*4 + j)*72 + ct*16 + lr;
          EsH[ea] = eh;
          EsL[ea] = tobf(e - frombf(eh));
        }
      }
      __syncthreads();
#pragma unroll
      for (int ks=0; ks<2; ks++){
        bf16x8 ahh = *(const bf16x8*)&EsH[(w*16 + lr)*72 + ks*32 + lk*8];
        bf16x8 ahl = *(const bf16x8*)&EsL[(w*16 + lr)*72 + ks*32 + lk*8];
#pragma unroll
        for (int dt=0; dt<4; dt++){
          bf16x8 bv = *(const bf16x8*)&Vt[(dt*16 + lr)*72 + ks*32 + lk*8];
          num[dt] = __builtin_amdgcn_mfma_f32_16x16x32_bf16(ahh, bv, num[dt], 0,0,0);
          num[dt] = __builtin_amdgcn_mfma_f32_16x16x32_bf16(ahl, bv, num[dt], 0,0,0);
        }
      }
    }
  }

  if constexpr (PASS==1){
#pragma unroll
    for (int j=0;j<4;j++){
#pragma unroll
      for (int o=1;o<16;o<<=1) rmx[j] = fmaxf(rmx[j], __shfl_xor(rmx[j], o, 64));
    }
    if (lr == 0){
#pragma unroll
      for (int j=0;j<4;j++)
        if (qr[j] < NN) rowmax[(size_t)bh*NN + qr[j]] = rmx[j];
    }
    gmn = wmin(gmn); gmx = wmax(gmx);
    if (l==0){ redn[w]=gmn; redx[w]=gmx; }
    __syncthreads();
    if (tid==0){
      float mn = fminf(fminf(redn[0],redn[1]), fminf(redn[2],redn[3]));
      float mx = fmaxf(fmaxf(redx[0],redx[1]), fmaxf(redx[2],redx[3]));
      atomicMin(&slots[6], fenc(mn));
      atomicMax(&slots[7], fenc(mx));
    }
  } else {
#pragma unroll
    for (int j=0;j<4;j++){
#pragma unroll
      for (int o=1;o<16;o<<=1) den[j] += __shfl_xor(den[j], o, 64);
    }
    int b = bh/NH, h = bh - b*NH;
    float gmn2 = 3.4e38f, gmx2 = -3.4e38f;
#pragma unroll
    for (int dt=0;dt<4;dt++){
#pragma unroll
      for (int j=0;j<4;j++){
        if (qr[j] < NN){
          float oo = num[dt][j] * sv / den[j];
          outp[((size_t)b*NN + qr[j])*NC + h*ND + dt*16 + lr] = oo;
          gmn2 = fminf(gmn2, oo); gmx2 = fmaxf(gmx2, oo);
        }
      }
    }
    gmn2 = wmin(gmn2); gmx2 = wmax(gmx2);
    if (l==0){ redn[w]=gmn2; redx[w]=gmx2; }
    __syncthreads();
    if (tid==0){
      float mn = fminf(fminf(redn[0],redn[1]), fminf(redn[2],redn[3]));
      float mx = fmaxf(fmaxf(redx[0],redx[1]), fmaxf(redx[2],redx[3]));
      atomicMin(&slots[8], fenc(mn));
      atomicMax(&slots[9], fenc(mx));
    }
  }
}

__global__ __launch_bounds__(256) void k_fq_inplace(float* x, long n4, const u32* __restrict__ slots){
  float mn = fdec(slots[0]), mx = fdec(slots[1]);
  float s = fmaxf((mx-mn)/255.0f, 1e-8f);
  float z = rintf(-mn/s);
  for (long i = (long)blockIdx.x*blockDim.x + threadIdx.x; i < n4; i += (long)gridDim.x*blockDim.x){
    float4 v = ((float4*)x)[i];
    v.x = fqdq(v.x,s,z); v.y = fqdq(v.y,s,z); v.z = fqdq(v.z,s,z); v.w = fqdq(v.w,s,z);
    ((float4*)x)[i] = v;
  }
}

extern "C" void kernel_launch(void* const* d_in, const int* in_sizes, int n_in,
                              void* d_out, int out_size, void* d_ws, size_t ws_size,
                              hipStream_t stream) {
  (void)in_sizes; (void)n_in; (void)out_size; (void)ws_size;
  const float* x      = (const float*)d_in[0];
  const float* w_qkv  = (const float*)d_in[1];
  const float* b_qkv  = (const float*)d_in[2];
  const float* w_proj = (const float*)d_in[3];
  const float* b_proj = (const float*)d_in[4];
  float* out = (float*)d_out;

  u32*   slots  = (u32*)d_ws;
  u16*   B1     = (u16*)((char*)d_ws + 256);        // 2304*768 u16
  u16*   B2     = B1 + (size_t)NO3*NC;              //  768*768 u16
  float* s1     = (float*)(B2 + (size_t)NC*NC);     // 2304
  float* s2     = s1 + NO3;                         //  768
  float* rowmax = s2 + NC;                          // 768*197
  float* qkv    = rowmax + (size_t)NBH*NN;          // 12608*2304 f32 (116.2 MB)
  u16*   codesR = (u16*)(qkv + (size_t)NM*NO3);     // 58.1 MB shared region:
  u16*   xhl    = codesR;                           //   [M][1536] bf16, dies at transcode
  u16*   codes  = codesR;                           //   attn codes, dies at transcode2
  u16*   codes2 = codesR;                           //   [M][768] bf16
  float* outpv  = qkv;                              // ALIAS: qkv raw dead after transcode

  k_init<<<1, 64, 0, stream>>>(slots);
  k_wquant<<<NO3 + NC, 256, 0, stream>>>(w_qkv, w_proj, B1, s1, B2, s2);
  k_xsplit<<<1024, 256, 0, stream>>>(x, xhl);
  k_gemm_bf16<0><<<18*99, 256, 0, stream>>>(xhl, 1536, B1, s1, b_qkv, qkv, NO3, 18, nullptr, slots);
  k_transcode<<<2048, 256, 0, stream>>>(qkv, codes, slots);
  k_attn<1><<<dim3(4, NBH), 256, 0, stream>>>(codes, rowmax, slots, nullptr);
  k_attn<2><<<dim3(4, NBH), 256, 0, stream>>>(codes, rowmax, slots, outpv);
  k_transcode2<<<1024, 256, 0, stream>>>(outpv, codes2, slots + 8);
  k_gemm_bf16<1><<<6*99, 256, 0, stream>>>(codes2, 768, B2, s2, b_proj, out, NC, 6, slots + 8, slots + 10);
  k_fq_inplace<<<1024, 256, 0, stream>>>(out, (long)NM*NC/4, slots + 10);
}